// Round 6
// baseline (364.128 us; speedup 1.0000x reference)
//
#include <hip/hip_runtime.h>

// ---------------------------------------------------------------------------
// FCGF_point_att2_ican_fc: per-point score -> global BN(1) -> per-segment
// softmax attention pooling -> FC(32,64) -> BN(64).
//
// R6: 2 dispatches (no cooperative launch — R4 showed it never runs under
// graph capture). R5's regression root-caused: 30 KB static LDS capped
// residency at 2 blocks/CU (Occupancy 24%) -> latency-bound 161 us k_pool.
// Fix: epilogue scratch (pooled/hmat) lives in GLOBAL ws (one L2-hot block
// uses it); consts reduction via double shuffle butterflies; LDS ~1.3 KB.
//   A (k_stats): z-stat double partials; block 0 zeros gnum/gden/counter.
//   B (k_pool):  per-block redundant consts reduction (16 KB L2-hot read),
//                pool loop, 33 atomics/block, decoupled last-block epilogue.
// All register arrays statically indexed (R3: dynamic idx => scratch spill).
// ---------------------------------------------------------------------------

#define EPS 1e-5f
#define NSB 1024          // kernel A blocks == # of double-pair partials
#define CHUNKS 16         // kernel B: blocks per segment

// workspace layout (bytes)
#define WS_DPART   0          // double[2*NSB] = 16384
#define WS_GNUM    16384      // float[64*32]  =  8192
#define WS_GDEN    24576      // float[64]
#define WS_CNT     24832      // unsigned int
#define WS_POOLED  24960      // float[64*32]  =  8192 (epilogue scratch)
#define WS_HMAT    33152      // float[64*64]  = 16384 (epilogue scratch)

// ---------------------------------------------------------------------------
// Kernel A: grid-stride z-stats; per-block double partials (sum z, sum z^2).
// Block 0 zeros kernel B's accumulators (visible at kernel boundary).
__global__ __launch_bounds__(256, 4) void k_stats(const float* __restrict__ x,
                                                  const float* __restrict__ w1,
                                                  const float* __restrict__ b1,
                                                  int N, int B,
                                                  double* __restrict__ dpart,
                                                  float* __restrict__ gnum,
                                                  float* __restrict__ gden,
                                                  unsigned int* __restrict__ cnt) {
    const int tid = threadIdx.x;
    if (blockIdx.x == 0) {
        for (int i = tid; i < B * 32; i += 256) gnum[i] = 0.f;
        if (tid < B) gden[tid] = 0.f;
        if (tid == 0) *cnt = 0u;
    }

    const float b1v = b1[0];
    const float4* __restrict__ xv = (const float4*)x;
    const int stride = gridDim.x * 256;

    double accZ = 0.0, accZZ = 0.0;
    for (int row = blockIdx.x * 256 + tid; row < N; row += stride) {
        const float4* __restrict__ rp = xv + (size_t)row * 8;
        float4 v[8];
#pragma unroll
        for (int i = 0; i < 8; ++i) v[i] = rp[i];
        float z = b1v;
#pragma unroll
        for (int i = 0; i < 8; ++i) {
            z = fmaf(v[i].x, w1[4 * i + 0], z);
            z = fmaf(v[i].y, w1[4 * i + 1], z);
            z = fmaf(v[i].z, w1[4 * i + 2], z);
            z = fmaf(v[i].w, w1[4 * i + 3], z);
        }
        accZ  += (double)z;
        accZZ += (double)z * (double)z;
    }

    // wave butterfly on doubles, then 4-entry LDS
    __shared__ double sdz[4], sdzz[4];
#pragma unroll
    for (int msk = 1; msk < 64; msk <<= 1) {
        accZ  += __shfl_xor(accZ,  msk);
        accZZ += __shfl_xor(accZZ, msk);
    }
    const int wave = tid >> 6;
    if ((tid & 63) == 0) { sdz[wave] = accZ; sdzz[wave] = accZZ; }
    __syncthreads();
    if (tid == 0) {
        dpart[2 * blockIdx.x]     = sdz[0] + sdz[1] + sdz[2] + sdz[3];
        dpart[2 * blockIdx.x + 1] = sdzz[0] + sdzz[1] + sdzz[2] + sdzz[3];
    }
}

// ---------------------------------------------------------------------------
// Kernel B: redundant consts reduction -> pool -> atomics -> last-block-done
// epilogue (scratch in global ws; LDS kept tiny for occupancy).
__global__ __launch_bounds__(256, 4) void k_pool(const float* __restrict__ x,
                                                 const int* __restrict__ length,
                                                 const float* __restrict__ w1,
                                                 const float* __restrict__ b1,
                                                 const float* __restrict__ g1,
                                                 const float* __restrict__ beta1,
                                                 const float* __restrict__ W2,
                                                 const float* __restrict__ b2,
                                                 const float* __restrict__ g2,
                                                 const float* __restrict__ beta2,
                                                 float* __restrict__ out,
                                                 int N, int B,
                                                 const double* __restrict__ dpart,
                                                 float* __restrict__ gnum,
                                                 float* __restrict__ gden,
                                                 unsigned int* __restrict__ cnt,
                                                 float* __restrict__ pooledg,
                                                 float* __restrict__ hmatg) {
    const int tid = threadIdx.x;
    const int c = blockIdx.x, b = blockIdx.y;
    const int nblk = gridDim.x * gridDim.y;
    const int wave = tid >> 6;
    const int lane = tid & 63;

    __shared__ double sdz[4], sdzz[4];
    __shared__ float sc[2];
    __shared__ int sLen[64];
    __shared__ int soff;
    __shared__ float sred[4][33];
    __shared__ unsigned int sold;
    __shared__ float smu[64], sisd[64];

    if (tid < B) sLen[tid] = length[tid];

    // --- redundant consts reduction (16 KB, L2-hot) -------------------------
    double az = 0.0, azz = 0.0;
#pragma unroll
    for (int k = 0; k < NSB / 256; ++k) {
        int i = k * 256 + tid;
        az  += dpart[2 * i];
        azz += dpart[2 * i + 1];
    }
#pragma unroll
    for (int msk = 1; msk < 64; msk <<= 1) {
        az  += __shfl_xor(az,  msk);
        azz += __shfl_xor(azz, msk);
    }
    if (lane == 0) { sdz[wave] = az; sdzz[wave] = azz; }
    __syncthreads();
    if (tid == 0) {
        double sZ  = sdz[0] + sdz[1] + sdz[2] + sdz[3];
        double sZZ = sdzz[0] + sdzz[1] + sdzz[2] + sdzz[3];
        double mu  = sZ / (double)N;
        double var = sZZ / (double)N - mu * mu;
        float c1 = (float)((double)g1[0] / sqrt(var + (double)EPS));
        sc[0] = c1;
        sc[1] = beta1[0] - (float)(c1 * mu);
        int o = 0;
        for (int i = 0; i < b; ++i) o += sLen[i];
        soff = o;
    }
    __syncthreads();

    const float c1 = sc[0], c2 = sc[1];
    const int off = soff, len = sLen[b];
    const int rpc = (len + CHUNKS - 1) / CHUNKS;
    const int r0 = c * rpc, r1 = min(r0 + rpc, len);

    const float b1v = b1[0];
    const float4* __restrict__ xv = (const float4*)x;

    // --- pool loop ----------------------------------------------------------
    float4 acc[8];
#pragma unroll
    for (int i = 0; i < 8; ++i) acc[i] = make_float4(0.f, 0.f, 0.f, 0.f);
    float accE = 0.f;

    for (int r = r0 + tid; r < r1; r += 256) {
        const float4* __restrict__ rp = xv + (size_t)(off + r) * 8;
        float4 v[8];
#pragma unroll
        for (int i = 0; i < 8; ++i) v[i] = rp[i];
        float z = b1v, m = 0.f;
#pragma unroll
        for (int i = 0; i < 8; ++i) {
            z = fmaf(v[i].x, w1[4 * i + 0], z);
            z = fmaf(v[i].y, w1[4 * i + 1], z);
            z = fmaf(v[i].z, w1[4 * i + 2], z);
            z = fmaf(v[i].w, w1[4 * i + 3], z);
            m += v[i].x + v[i].y + v[i].z + v[i].w;
        }
        float s = (c1 * z + c2) * m * 0.03125f;
        float e = __expf(s);
#pragma unroll
        for (int i = 0; i < 8; ++i) {
            acc[i].x = fmaf(e, v[i].x, acc[i].x);
            acc[i].y = fmaf(e, v[i].y, acc[i].y);
            acc[i].z = fmaf(e, v[i].z, acc[i].z);
            acc[i].w = fmaf(e, v[i].w, acc[i].w);
        }
        accE += e;
    }

    // --- wave butterfly (static indices), cross-wave via LDS, 33 atomics ----
#pragma unroll
    for (int msk = 1; msk < 64; msk <<= 1) {
#pragma unroll
        for (int i = 0; i < 8; ++i) {
            acc[i].x += __shfl_xor(acc[i].x, msk);
            acc[i].y += __shfl_xor(acc[i].y, msk);
            acc[i].z += __shfl_xor(acc[i].z, msk);
            acc[i].w += __shfl_xor(acc[i].w, msk);
        }
        accE += __shfl_xor(accE, msk);
    }
    if (lane == 0) {
#pragma unroll
        for (int i = 0; i < 8; ++i) {
            sred[wave][4 * i + 0] = acc[i].x;
            sred[wave][4 * i + 1] = acc[i].y;
            sred[wave][4 * i + 2] = acc[i].z;
            sred[wave][4 * i + 3] = acc[i].w;
        }
        sred[wave][32] = accE;
    }
    __syncthreads();
    if (tid < 33) {
        float s = sred[0][tid] + sred[1][tid] + sred[2][tid] + sred[3][tid];
        if (tid < 32) atomicAdd(&gnum[b * 32 + tid], s);
        else          atomicAdd(&gden[b], s);
    }

    // --- decoupled last-block-done epilogue ---------------------------------
    __threadfence();
    __syncthreads();
    if (tid == 0) sold = atomicAdd(cnt, 1u);
    __syncthreads();
    if (sold != (unsigned int)(nblk - 1)) return;
    __threadfence();

    // pooled -> global ws (L2-hot; single block)
    for (int i = tid; i < B * 32; i += 256) {
        int bb = i >> 5;
        float num = atomicAdd(&gnum[i], 0.f);     // device-scope reads
        float den = atomicAdd(&gden[bb], 0.f);
        pooledg[i] = num / (den * (float)sLen[bb]);
    }
    __threadfence_block();
    __syncthreads();

    const int j = tid & 63;
    const int g = tid >> 6;
    for (int r = 0; r < 16; ++r) {
        int bb = g * 16 + r;
        if (bb < B) {
            float hv = b2[j];
            for (int k = 0; k < 32; ++k)
                hv += pooledg[bb * 32 + k] * W2[k * 64 + j];
            hmatg[bb * 64 + j] = hv;
        }
    }
    __threadfence_block();
    __syncthreads();

    if (tid < 64) {
        float m = 0.f;
        for (int bb = 0; bb < B; ++bb) m += hmatg[bb * 64 + tid];
        m /= (float)B;
        float v = 0.f;
        for (int bb = 0; bb < B; ++bb) { float d = hmatg[bb * 64 + tid] - m; v += d * d; }
        v /= (float)B;
        smu[tid] = m;
        sisd[tid] = rsqrtf(v + EPS);
    }
    __syncthreads();

    for (int r = 0; r < 16; ++r) {
        int bb = g * 16 + r;
        if (bb < B) {
            int idx = bb * 64 + j;
            out[idx] = g2[j] * (hmatg[idx] - smu[j]) * sisd[j] + beta2[j];
        }
    }
}

// ---------------------------------------------------------------------------
extern "C" void kernel_launch(void* const* d_in, const int* in_sizes, int n_in,
                              void* d_out, int out_size, void* d_ws, size_t ws_size,
                              hipStream_t stream) {
    const float* x      = (const float*)d_in[0];
    const int*   length = (const int*)  d_in[1];
    const float* w1     = (const float*)d_in[2];
    const float* b1     = (const float*)d_in[3];
    const float* g1     = (const float*)d_in[4];
    const float* beta1  = (const float*)d_in[5];
    const float* W2     = (const float*)d_in[6];
    const float* b2     = (const float*)d_in[7];
    const float* g2     = (const float*)d_in[8];
    const float* beta2  = (const float*)d_in[9];
    float* out = (float*)d_out;

    const int N = in_sizes[0] / 32;
    const int B = in_sizes[1];

    char* ws = (char*)d_ws;
    double*       dpart   = (double*)      (ws + WS_DPART);
    float*        gnum    = (float*)       (ws + WS_GNUM);
    float*        gden    = (float*)       (ws + WS_GDEN);
    unsigned int* cnt     = (unsigned int*)(ws + WS_CNT);
    float*        pooledg = (float*)       (ws + WS_POOLED);
    float*        hmatg   = (float*)       (ws + WS_HMAT);

    k_stats<<<NSB, 256, 0, stream>>>(x, w1, b1, N, B, dpart, gnum, gden, cnt);
    k_pool <<<dim3(CHUNKS, B), 256, 0, stream>>>(x, length, w1, b1, g1, beta1,
                                                 W2, b2, g2, beta2, out, N, B,
                                                 dpart, gnum, gden, cnt,
                                                 pooledg, hmatg);
}

// Round 7
// 257.202 us; speedup vs baseline: 1.4157x; 1.4157x over previous
//
#include <hip/hip_runtime.h>

// ---------------------------------------------------------------------------
// FCGF_point_att2_ican_fc: per-point score -> global BN(1) -> per-segment
// softmax attention pooling -> FC(32,64) -> BN(64).
//
// R7: back to R3's proven 4-dispatch skeleton (R4-R6 fusion all lost), but
// the two big passes use a global_load_lds wave-private pipeline:
//   - stage = 1 KB = 8 rows (64 lanes x 16 B DMA, no VGPR destination)
//   - ring of 4 slots per wave, 3 stages in flight (s_waitcnt vmcnt(2))
//   - lane l owns row l>>3, colgroup l&7; shuffles xor{1,2,4} give z/rowsum
//   - pool accumulator = ONE float4 + accE per lane (colgroup fixed)
// In-flight bytes/CU = 32 waves x 3 KB = 96 KB >> 9.2 KB Little's-law need
// -> HBM-BW-bound, not latency-bound (R6: 8 loads/wave x 7 waves = 0.7 TB/s).
// ---------------------------------------------------------------------------

#define EPS 1e-5f
#define NSB 2048          // k_stats blocks (= # of double-pair partials)
#define CHUNKS 32         // k_pool blocks per segment
#define PIPE 3            // DMA stages in flight
#define RING 4            // LDS ring slots per wave

// workspace layout (bytes)
#define WS_DPART   0          // double[2*NSB] = 32768
#define WS_CONSTS  32768      // float c1, c2
#define WS_OFFS    32800      // int[65]
#define WS_GNUM    33280      // float[64*32]
#define WS_GDEN    41472      // float[64]

__device__ __forceinline__ void ldsdma16(const void* g, void* l) {
    __builtin_amdgcn_global_load_lds(
        (const __attribute__((address_space(1))) void*)g,
        (__attribute__((address_space(3))) void*)l, 16, 0, 0);
}

__device__ __forceinline__ void wait_stage(int rem) {
    // wave-uniform branch; stage complete when <= rem newer ops outstanding
    if (rem >= 2)      asm volatile("s_waitcnt vmcnt(2)" ::: "memory");
    else if (rem == 1) asm volatile("s_waitcnt vmcnt(1)" ::: "memory");
    else               asm volatile("s_waitcnt vmcnt(0)" ::: "memory");
}

// ---------------------------------------------------------------------------
// Pass 1: z = x.w1 + b1 per row; per-block double partials (sum z, sum z^2).
__global__ __launch_bounds__(256, 8) void k_stats(const float* __restrict__ x,
                                                  const float* __restrict__ w1,
                                                  const float* __restrict__ b1,
                                                  int N,
                                                  double* __restrict__ dpart) {
    __shared__ float4 ring[4][RING][64];
    __shared__ double sdz[4], sdzz[4];
    const int tid = threadIdx.x;
    const int w = tid >> 6, lane = tid & 63;
    const int q = lane & 7;

    const float4 w4 = ((const float4*)w1)[q];
    const float b1v = b1[0];
    // drain scalar loads so no compiler waits land inside the pipeline
    asm volatile("s_waitcnt vmcnt(0)" ::: "memory");

    const float4* __restrict__ xv = (const float4*)x;
    const int Nm1 = N - 1;
    const int rpb = (N + NSB - 1) / NSB;
    const int wpr = (rpb + 3) >> 2;
    const int br0 = blockIdx.x * rpb;
    const int wr0 = br0 + w * wpr;
    const int wend = min(min(wr0 + wpr, br0 + rpb), N);
    const int span = wend - wr0;
    const int nst = (span + 7) >> 3;

    double accZ = 0.0, accZZ = 0.0;

    if (span > 0) {
        for (int p = 0; p < PIPE && p < nst; ++p) {
            int row = min(wr0 + p * 8 + (lane >> 3), Nm1);
            ldsdma16(xv + (size_t)row * 8 + q, &ring[w][p & (RING - 1)][0]);
        }
        for (int st = 0; st < nst; ++st) {
            wait_stage(nst - 1 - st < PIPE - 1 ? nst - 1 - st : PIPE - 1);
            float4 v = ring[w][st & (RING - 1)][lane];
            asm volatile("" ::: "memory");
            if (st + PIPE < nst) {
                int row = min(wr0 + (st + PIPE) * 8 + (lane >> 3), Nm1);
                ldsdma16(xv + (size_t)row * 8 + q,
                         &ring[w][(st + PIPE) & (RING - 1)][0]);
            }
            float zp = v.x * w4.x + v.y * w4.y + v.z * w4.z + v.w * w4.w;
            zp += __shfl_xor(zp, 1);
            zp += __shfl_xor(zp, 2);
            zp += __shfl_xor(zp, 4);
            int row = wr0 + st * 8 + (lane >> 3);
            float z = (row < wend) ? (zp + b1v) : 0.f;
            accZ  += (double)z;
            accZZ += (double)z * (double)z;
        }
    }
    // each row lives in exactly one 8-lane group (lanes within group equal);
    // xor over bits 3-5 sums across groups once per row
#pragma unroll
    for (int m = 8; m <= 32; m <<= 1) {
        accZ  += __shfl_xor(accZ, m);
        accZZ += __shfl_xor(accZZ, m);
    }
    if (lane == 0) { sdz[w] = accZ; sdzz[w] = accZZ; }
    __syncthreads();
    if (tid == 0) {
        dpart[2 * blockIdx.x]     = sdz[0] + sdz[1] + sdz[2] + sdz[3];
        dpart[2 * blockIdx.x + 1] = sdzz[0] + sdzz[1] + sdzz[2] + sdzz[3];
    }
}

// ---------------------------------------------------------------------------
// Reduce partials -> c1, c2; prefix-sum lengths; zero gnum/gden.
__global__ __launch_bounds__(256) void k_consts(const double* __restrict__ dpart,
                                                const int* __restrict__ length,
                                                const float* __restrict__ g1,
                                                const float* __restrict__ beta1,
                                                int N, int B,
                                                float* __restrict__ consts,
                                                int* __restrict__ offs,
                                                float* __restrict__ gnum,
                                                float* __restrict__ gden) {
    __shared__ double sZ[256], sZZ[256];
    const int tid = threadIdx.x;

    for (int i = tid; i < B * 32; i += 256) gnum[i] = 0.f;
    if (tid < B) gden[tid] = 0.f;

    double aZ = 0.0, aZZ = 0.0;
    for (int i = tid; i < NSB; i += 256) {
        aZ  += dpart[2 * i];
        aZZ += dpart[2 * i + 1];
    }
    sZ[tid] = aZ; sZZ[tid] = aZZ;
    __syncthreads();
    for (int s = 128; s > 0; s >>= 1) {
        if (tid < s) { sZ[tid] += sZ[tid + s]; sZZ[tid] += sZZ[tid + s]; }
        __syncthreads();
    }
    if (tid == 0) {
        double mu  = sZ[0] / (double)N;
        double var = sZZ[0] / (double)N - mu * mu;
        float c1 = (float)((double)g1[0] / sqrt(var + (double)EPS));
        consts[0] = c1;
        consts[1] = beta1[0] - (float)(c1 * mu);
        int o = 0;
        offs[0] = 0;
        for (int b = 0; b < B; ++b) { o += length[b]; offs[b + 1] = o; }
    }
}

// ---------------------------------------------------------------------------
// Pass 2: s = (c1*z + c2) * rowmean; e = exp(s); per-segment sum(e*x), sum(e).
// Accumulator: one float4 (lane's fixed colgroup) + accE.
__global__ __launch_bounds__(256, 8) void k_pool(const float* __restrict__ x,
                                                 const float* __restrict__ w1,
                                                 const float* __restrict__ b1,
                                                 const float* __restrict__ consts,
                                                 const int* __restrict__ offs,
                                                 int N,
                                                 float* __restrict__ gnum,
                                                 float* __restrict__ gden) {
    __shared__ float4 ring[4][RING][64];
    __shared__ float sred[4][33];
    const int tid = threadIdx.x;
    const int w = tid >> 6, lane = tid & 63;
    const int q = lane & 7;
    const int c = blockIdx.x, b = blockIdx.y;

    const float4 w4 = ((const float4*)w1)[q];
    const float b1v = b1[0];
    const float c1 = consts[0], c2 = consts[1];
    const int off = offs[b], len = offs[b + 1] - off;
    asm volatile("s_waitcnt vmcnt(0)" ::: "memory");

    const int rpc = (len + CHUNKS - 1) / CHUNKS;
    const int r0 = c * rpc;
    const int r1 = min(r0 + rpc, len);
    const int wpr = (rpc + 3) >> 2;
    const int wrel0 = r0 + w * wpr;
    const int wrel1 = min(wrel0 + wpr, r1);
    const int span = wrel1 - wrel0;
    const int nst = (span + 7) >> 3;
    const int wr0 = off + wrel0;
    const int wend = off + wrel1;
    const float4* __restrict__ xv = (const float4*)x;
    const int Nm1 = N - 1;

    float4 acc = make_float4(0.f, 0.f, 0.f, 0.f);
    float accE = 0.f;

    if (span > 0) {
        for (int p = 0; p < PIPE && p < nst; ++p) {
            int row = min(wr0 + p * 8 + (lane >> 3), Nm1);
            ldsdma16(xv + (size_t)row * 8 + q, &ring[w][p & (RING - 1)][0]);
        }
        for (int st = 0; st < nst; ++st) {
            wait_stage(nst - 1 - st < PIPE - 1 ? nst - 1 - st : PIPE - 1);
            float4 v = ring[w][st & (RING - 1)][lane];
            asm volatile("" ::: "memory");
            if (st + PIPE < nst) {
                int row = min(wr0 + (st + PIPE) * 8 + (lane >> 3), Nm1);
                ldsdma16(xv + (size_t)row * 8 + q,
                         &ring[w][(st + PIPE) & (RING - 1)][0]);
            }
            float zp = v.x * w4.x + v.y * w4.y + v.z * w4.z + v.w * w4.w;
            float mp = v.x + v.y + v.z + v.w;
            zp += __shfl_xor(zp, 1);  mp += __shfl_xor(mp, 1);
            zp += __shfl_xor(zp, 2);  mp += __shfl_xor(mp, 2);
            zp += __shfl_xor(zp, 4);  mp += __shfl_xor(mp, 4);
            float z = zp + b1v;
            float s = (c1 * z + c2) * mp * 0.03125f;
            float e = __expf(s);
            int row = wr0 + st * 8 + (lane >> 3);
            e = (row < wend) ? e : 0.f;
            acc.x = fmaf(e, v.x, acc.x);
            acc.y = fmaf(e, v.y, acc.y);
            acc.z = fmaf(e, v.z, acc.z);
            acc.w = fmaf(e, v.w, acc.w);
            accE += e;
        }
    }
    // sum across the 8 groups (same q) — each row counted exactly once
#pragma unroll
    for (int m = 8; m <= 32; m <<= 1) {
        acc.x += __shfl_xor(acc.x, m);
        acc.y += __shfl_xor(acc.y, m);
        acc.z += __shfl_xor(acc.z, m);
        acc.w += __shfl_xor(acc.w, m);
        accE  += __shfl_xor(accE, m);
    }
    if (lane < 8) {
        sred[w][4 * lane + 0] = acc.x;
        sred[w][4 * lane + 1] = acc.y;
        sred[w][4 * lane + 2] = acc.z;
        sred[w][4 * lane + 3] = acc.w;
        if (lane == 0) sred[w][32] = accE;
    }
    __syncthreads();
    if (tid < 33) {
        float s = sred[0][tid] + sred[1][tid] + sred[2][tid] + sred[3][tid];
        if (tid < 32) atomicAdd(&gnum[b * 32 + tid], s);
        else          atomicAdd(&gden[b], s);
    }
}

// ---------------------------------------------------------------------------
// Epilogue: pooled = num/(den*len); h = pooled @ W2 + b2; BN over B rows.
__global__ __launch_bounds__(256) void k_head(const float* __restrict__ gnum,
                                              const float* __restrict__ gden,
                                              const int* __restrict__ length,
                                              const float* __restrict__ W2,
                                              const float* __restrict__ b2,
                                              const float* __restrict__ g2,
                                              const float* __restrict__ beta2,
                                              float* __restrict__ out, int B) {
    __shared__ float pooled[64 * 32];
    __shared__ float h[64 * 64];
    __shared__ float mu2[64], isd[64];
    const int tid = threadIdx.x;

    for (int i = tid; i < B * 32; i += 256) {
        int bb = i >> 5;
        pooled[i] = gnum[i] / (gden[bb] * (float)length[bb]);
    }
    __syncthreads();

    const int j = tid & 63;
    const int g = tid >> 6;
    for (int r = 0; r < 16; ++r) {
        int bb = g * 16 + r;
        if (bb < B) {
            float hv = b2[j];
            for (int k = 0; k < 32; ++k) hv += pooled[bb * 32 + k] * W2[k * 64 + j];
            h[bb * 64 + j] = hv;
        }
    }
    __syncthreads();

    if (tid < 64) {
        float m = 0.f;
        for (int bb = 0; bb < B; ++bb) m += h[bb * 64 + tid];
        m /= (float)B;
        float v = 0.f;
        for (int bb = 0; bb < B; ++bb) { float d = h[bb * 64 + tid] - m; v += d * d; }
        v /= (float)B;
        mu2[tid] = m;
        isd[tid] = rsqrtf(v + EPS);
    }
    __syncthreads();

    for (int r = 0; r < 16; ++r) {
        int bb = g * 16 + r;
        if (bb < B) {
            int idx = bb * 64 + j;
            out[idx] = g2[j] * (h[idx] - mu2[j]) * isd[j] + beta2[j];
        }
    }
}

// ---------------------------------------------------------------------------
extern "C" void kernel_launch(void* const* d_in, const int* in_sizes, int n_in,
                              void* d_out, int out_size, void* d_ws, size_t ws_size,
                              hipStream_t stream) {
    const float* x      = (const float*)d_in[0];
    const int*   length = (const int*)  d_in[1];
    const float* w1     = (const float*)d_in[2];
    const float* b1     = (const float*)d_in[3];
    const float* g1     = (const float*)d_in[4];
    const float* beta1  = (const float*)d_in[5];
    const float* W2     = (const float*)d_in[6];
    const float* b2     = (const float*)d_in[7];
    const float* g2     = (const float*)d_in[8];
    const float* beta2  = (const float*)d_in[9];
    float* out = (float*)d_out;

    const int N = in_sizes[0] / 32;
    const int B = in_sizes[1];

    char* ws = (char*)d_ws;
    double* dpart  = (double*)(ws + WS_DPART);
    float*  consts = (float*) (ws + WS_CONSTS);
    int*    offs   = (int*)   (ws + WS_OFFS);
    float*  gnum   = (float*) (ws + WS_GNUM);
    float*  gden   = (float*) (ws + WS_GDEN);

    k_stats <<<NSB, 256, 0, stream>>>(x, w1, b1, N, dpart);
    k_consts<<<1,   256, 0, stream>>>(dpart, length, g1, beta1, N, B,
                                      consts, offs, gnum, gden);
    k_pool  <<<dim3(CHUNKS, B), 256, 0, stream>>>(x, w1, b1, consts, offs, N,
                                                  gnum, gden);
    k_head  <<<1,   256, 0, stream>>>(gnum, gden, length, W2, b2, g2, beta2, out, B);
}